// Round 9
// baseline (217.524 us; speedup 1.0000x reference)
//
#include <hip/hip_runtime.h>
#include <stdint.h>

// SelfAttention: B=4, S=2048, D=1024, causal, single head of dim 1024.
// R14: R13 + pv pairing fix. Under the (R13-confirmed) round-robin %8
// block->XCD placement, CU c co-hosts blocks bid and bid+256. R13's pv map
// gave co-resident work sums of 8..22 units (tail = 22); new map q=r>>2,
// mb = q<8 ? 15-q : q-8 makes every co-resident pair sum to exactly 17
// units -> provably flat makespan. Scheduling-only change.

typedef unsigned short u16;
typedef __attribute__((ext_vector_type(8))) short shortx8;  // 8 bf16 (4 VGPRs)
typedef __attribute__((ext_vector_type(4))) float floatx4;

static constexpr int BB = 4;
static constexpr int SS = 2048;
static constexpr int DD = 1024;

__device__ __forceinline__ u16 f2bf(float f) {
  union { float f; uint32_t u; } c; c.f = f;
  uint32_t u = c.u;
  return (u16)((u + 0x7fffu + ((u >> 16) & 1u)) >> 16);  // RNE
}

#define GLOAD_LDS16(g, l)                                                              \
  __builtin_amdgcn_global_load_lds((const __attribute__((address_space(1))) void*)(g), \
                                   (__attribute__((address_space(3))) void*)(l), 16, 0, 0)

// 128x128 C-tile GEMM core, BK=64, XOR-swizzled LDS (proven 888 TF structure).
__device__ __forceinline__ void gemm_core_128(
    const u16* __restrict__ A, const u16* __restrict__ Bt,
    int lda, int ldb, int m0, int n0, int kend, floatx4 acc[4][4])
{
  __shared__ u16 lA[128 * 64];  // [row][64], physical chunks swizzled
  __shared__ u16 lB[128 * 64];
  const int t = threadIdx.x;
  const int w = t >> 6, l = t & 63;
  const int wm = w >> 1, wn = w & 1;
  const int sr = l >> 3;                          // staging row within 8-row group
  const int scq = ((l & 7) ^ (l >> 3)) * 8;       // swizzled SOURCE chunk (elems)

#pragma unroll
  for (int i = 0; i < 4; ++i)
#pragma unroll
    for (int j = 0; j < 4; ++j)
      acc[i][j] = (floatx4){0.f, 0.f, 0.f, 0.f};

  const u16* Ab = A + (size_t)m0 * lda;
  const u16* Bb = Bt + (size_t)n0 * ldb;

  for (int k0 = 0; k0 < kend; k0 += 64) {
#pragma unroll
    for (int i = 0; i < 4; ++i) {
      const int row = w * 32 + i * 8;
      GLOAD_LDS16(Ab + (size_t)(row + sr) * lda + k0 + scq, &lA[row * 64]);
      GLOAD_LDS16(Bb + (size_t)(row + sr) * ldb + k0 + scq, &lB[row * 64]);
    }
    __syncthreads();  // drains vmcnt before barrier -> LDS visible

#pragma unroll
    for (int ks = 0; ks < 2; ++ks) {
      const int ca = ((ks * 4 + (l >> 4)) ^ (l & 7)) * 8;  // physical chunk (elems)
      shortx8 af[4], bf[4];
#pragma unroll
      for (int i = 0; i < 4; ++i)
        af[i] = *(const shortx8*)&lA[(wm * 64 + i * 16 + (l & 15)) * 64 + ca];
#pragma unroll
      for (int i = 0; i < 4; ++i)
        bf[i] = *(const shortx8*)&lB[(wn * 64 + i * 16 + (l & 15)) * 64 + ca];
#pragma unroll
      for (int i = 0; i < 4; ++i)
#pragma unroll
        for (int j = 0; j < 4; ++j)
          acc[i][j] = __builtin_amdgcn_mfma_f32_16x16x32_bf16(af[i], bf[j], acc[i][j], 0, 0, 0);
    }
    __syncthreads();  // protect LDS before next stage
  }
}

// ---- kernel 0: prep, grid-strided: blocks 0..2047 convert x (4x float4 per
//      thread) + zero rs; blocks 2048..2815 build Wt (64x64 transpose tiles) ----
__global__ __launch_bounds__(256) void prep(const float* __restrict__ x,
                                            const float* __restrict__ WQ,
                                            const float* __restrict__ WK,
                                            const float* __restrict__ WV,
                                            u16* __restrict__ xb,
                                            u16* __restrict__ Wt,
                                            float* __restrict__ rs) {
  __shared__ float tile[64][65];
  const int bid = blockIdx.x;
  const int t = threadIdx.x;
  if (bid < 2048) {  // xb = bf16(x), 4 float4 per thread
#pragma unroll
    for (int k = 0; k < 4; ++k) {
      const size_t i = (size_t)bid * 1024 + k * 256 + t;
      if (i < 8192) rs[i] = 0.f;  // zero row-sum accumulators (blocks 0..7)
      float4 v = ((const float4*)x)[i];
      ushort4 o;
      o.x = f2bf(v.x); o.y = f2bf(v.y); o.z = f2bf(v.z); o.w = f2bf(v.w);
      ((ushort4*)xb)[i] = o;
    }
    return;
  }
  // Wt[n][k] = bf16(W[k][n]), 64x64 tiles through LDS
  const int r = bid - 2048;      // 0..767
  const int wsel = r >> 8;       // 0..2
  const int rr = r & 255;
  const int k0 = (rr >> 4) * 64, n0 = (rr & 15) * 64;
  const float* W = wsel == 0 ? WQ : (wsel == 1 ? WK : WV);
  const int tx = t & 63, ty = t >> 6;
#pragma unroll
  for (int i = 0; i < 16; ++i)
    tile[ty + i * 4][tx] = W[(size_t)(k0 + ty + i * 4) * DD + n0 + tx];
  __syncthreads();
  u16* dst = Wt + (size_t)wsel * DD * DD;
#pragma unroll
  for (int i = 0; i < 16; ++i)
    dst[(size_t)(n0 + ty + i * 4) * DD + k0 + tx] = f2bf(tile[tx][ty + i * 4]);
}

// ---- kernels 1a/1b: fused QKV projection, M=8192 N=3072 K=1024, split into
//      two half-N launches (768 blocks each). Q,K row-major bf16; V written
//      TRANSPOSED into Vt[b][d][s]. ----
__device__ __forceinline__ void qkv_body(int m0, int n0t,
                                         const u16* __restrict__ x,
                                         const u16* __restrict__ Wt,
                                         u16* __restrict__ Q,
                                         u16* __restrict__ K,
                                         u16* __restrict__ Vt) {
  floatx4 acc[4][4];
  gemm_core_128(x, Wt, DD, DD, m0, n0t, DD, acc);

  const int t = threadIdx.x, w = t >> 6, l = t & 63;
  const int wm = w >> 1, wn = w & 1;

  if (n0t >= 2048) {  // V tile: write transposed. Each lane: 4 contiguous s per (i,j).
    const int bb = m0 >> 11;
    const int s0 = (m0 & 2047) + wm * 64 + (l >> 4) * 4;
    u16* vt = Vt + (size_t)bb * DD * SS;
#pragma unroll
    for (int i = 0; i < 4; ++i)
#pragma unroll
      for (int j = 0; j < 4; ++j) {
        const int n = (n0t - 2048) + wn * 64 + j * 16 + (l & 15);
        const int s = s0 + i * 16;
        ushort4 o4;
        o4.x = f2bf(acc[i][j][0]);
        o4.y = f2bf(acc[i][j][1]);
        o4.z = f2bf(acc[i][j][2]);
        o4.w = f2bf(acc[i][j][3]);
        *(ushort4*)(vt + (size_t)n * SS + s) = o4;
      }
    return;
  }

  u16* out = (n0t < 1024) ? Q : K;
  const int n0 = n0t & 1023;
#pragma unroll
  for (int i = 0; i < 4; ++i)
#pragma unroll
    for (int j = 0; j < 4; ++j)
#pragma unroll
      for (int r = 0; r < 4; ++r) {
        const int m = m0 + wm * 64 + i * 16 + (l >> 4) * 4 + r;
        const int n = n0 + wn * 64 + j * 16 + (l & 15);
        out[(size_t)m * DD + n] = f2bf(acc[i][j][r]);
      }
}

__global__ __launch_bounds__(256, 3) void qkv_a(const u16* __restrict__ x,
                                                const u16* __restrict__ Wt,
                                                u16* __restrict__ Q,
                                                u16* __restrict__ K,
                                                u16* __restrict__ Vt) {
  qkv_body(blockIdx.x * 128, blockIdx.y * 128, x, Wt, Q, K, Vt);
}

__global__ __launch_bounds__(256, 3) void qkv_b(const u16* __restrict__ x,
                                                const u16* __restrict__ Wt,
                                                u16* __restrict__ Q,
                                                u16* __restrict__ K,
                                                u16* __restrict__ Vt) {
  qkv_body(blockIdx.x * 128, (blockIdx.y + 12) * 128, x, Wt, Q, K, Vt);
}

// ---- kernel 2: E = bf16(exp(Q K^T / 32)) lower-tri blocks (diag masked),
//      + atomic per-row sums rs. XCD-chunked: sorted tile s = (bid&7)*68 +
//      bid>>3 gives each XCD 68 consecutive (b,mb,nb) tiles -> Q panels
//      shared within runs, K panels reused across mb within the 4MB L2. ----
__global__ __launch_bounds__(256, 3) void scores_gemm(const u16* __restrict__ Q,
                                                      const u16* __restrict__ Kt,
                                                      u16* __restrict__ Scb,
                                                      float* __restrict__ rs) {
  const int bid = blockIdx.x;                 // 0..543
  const int s = (bid & 7) * 68 + (bid >> 3);  // XCD-chunked sorted index
  const int b = s / 136;
  const int tcode = s - b * 136;              // 0..135
  int mb = (int)((sqrtf(8.0f * (float)tcode + 1.0f) - 1.0f) * 0.5f);
  while ((mb + 1) * (mb + 2) / 2 <= tcode) ++mb;  // fixup fp error
  while (mb * (mb + 1) / 2 > tcode) --mb;
  const int nb = tcode - mb * (mb + 1) / 2;
  const int m0 = mb * 128, n0 = nb * 128;

  floatx4 acc[4][4];
  gemm_core_128(Q + (size_t)b * SS * DD, Kt + (size_t)b * SS * DD, DD, DD, m0, n0, DD, acc);

  u16* out = Scb + (size_t)b * SS * SS;
  float* rsb = rs + (size_t)b * SS;
  const int t = threadIdx.x, w = t >> 6, l = t & 63;
  const int wm = w >> 1, wn = w & 1;
  const bool diag = (mb == nb);

  float rsum[4][4];  // [i][r] partial row sums
#pragma unroll
  for (int i = 0; i < 4; ++i)
#pragma unroll
    for (int r = 0; r < 4; ++r) rsum[i][r] = 0.f;

#pragma unroll
  for (int i = 0; i < 4; ++i)
#pragma unroll
    for (int j = 0; j < 4; ++j)
#pragma unroll
      for (int r = 0; r < 4; ++r) {
        const int lm = wm * 64 + i * 16 + (l >> 4) * 4 + r;  // local row
        const int ln = wn * 64 + j * 16 + (l & 15);          // local col
        float e = __expf(acc[i][j][r] * 0.03125f);           // 1/sqrt(1024)
        if (diag && ln > lm) e = 0.f;                        // causal mask
        out[(size_t)(m0 + lm) * SS + (n0 + ln)] = f2bf(e);
        rsum[i][r] += e;
      }

  // reduce over the 16 col-lanes (xor bits 0..3 mix only same-row lanes)
#pragma unroll
  for (int i = 0; i < 4; ++i)
#pragma unroll
    for (int r = 0; r < 4; ++r) {
      float s2 = rsum[i][r];
      s2 += __shfl_xor(s2, 1, 64);
      s2 += __shfl_xor(s2, 2, 64);
      s2 += __shfl_xor(s2, 4, 64);
      s2 += __shfl_xor(s2, 8, 64);
      if ((l & 15) == 0)
        atomicAdd(&rsb[m0 + wm * 64 + i * 16 + (l >> 4) * 4 + r], s2);
    }
}

// ---- kernel 3: O = (E V) / rs (causal K-range), fp32 out.
//      XCD-chunked + flat pairing: xcd = bid&7 owns (b = xcd>>1, nb half =
//      xcd&1). r = bid>>3 (0..63), q = r>>2 (0..15): mb = q<8 ? 15-q : q-8.
//      Co-resident pairs (r, r+32) = (q, q+8) -> mb sums to 15 exactly ->
//      every CU carries 17 work-units. Longest tiles dispatch first.
//      Working set per XCD (1 P panel + 4 Vt panels ~2.5MB) fits L2. ----
__global__ __launch_bounds__(256, 3) void pv_gemm(const u16* __restrict__ P,
                                                  const u16* __restrict__ Vt,
                                                  const float* __restrict__ rs,
                                                  float* __restrict__ out) {
  const int bid = blockIdx.x;     // 0..511
  const int xcd = bid & 7, r = bid >> 3;       // r 0..63
  const int q = r >> 2;                        // 0..15
  const int b = xcd >> 1;
  const int nb = (xcd & 1) * 4 + (r & 3);
  const int mb = (q < 8) ? (15 - q) : (q - 8);
  const int m0 = mb * 128, n0 = nb * 128;
  floatx4 acc[4][4];
  // rows m0..m0+127 only attend to keys k < m0+128
  gemm_core_128(P + (size_t)b * SS * SS, Vt + (size_t)b * DD * SS, SS, SS, m0, n0, m0 + 128, acc);

  float* o = out + (size_t)b * SS * DD;
  const float* rsb = rs + (size_t)b * SS;
  const int t = threadIdx.x, w = t >> 6, l = t & 63;
  const int wm = w >> 1, wn = w & 1;
#pragma unroll
  for (int i = 0; i < 4; ++i)
#pragma unroll
    for (int r2 = 0; r2 < 4; ++r2) {
      const int m = m0 + wm * 64 + i * 16 + (l >> 4) * 4 + r2;
      const float inv = 1.0f / rsb[m];   // row normalization (linear)
#pragma unroll
      for (int j2 = 0; j2 < 4; ++j2) {
        const int n = n0 + wn * 64 + j2 * 16 + (l & 15);
        o[(size_t)m * DD + n] = acc[i][j2][r2] * inv;
      }
    }
}

extern "C" void kernel_launch(void* const* d_in, const int* in_sizes, int n_in,
                              void* d_out, int out_size, void* d_ws, size_t ws_size,
                              hipStream_t stream) {
  const float* x  = (const float*)d_in[0];
  const float* WQ = (const float*)d_in[1];
  const float* WK = (const float*)d_in[2];
  const float* WV = (const float*)d_in[3];
  float* out = (float*)d_out;

  // workspace carve (bytes), ~88MB peak:
  //   Wt 6M | Q 16M | K 16M | Vt 16M | Scb(E) 32M | rs 32K, with xb (16M)
  //   aliased into Scb's tail half (xb dead before scores writes Scb).
  char* ws = (char*)d_ws;
  const size_t WT_OFF = 0;
  const size_t Q_OFF  = WT_OFF + (size_t)3072 * 1024 * 2;        // +6M
  const size_t K_OFF  = Q_OFF + (size_t)BB * SS * DD * 2;        // +16M
  const size_t VT_OFF = K_OFF + (size_t)BB * SS * DD * 2;        // +16M
  const size_t SC_OFF = VT_OFF + (size_t)BB * SS * DD * 2;       // +16M
  const size_t XB_OFF = SC_OFF + (size_t)BB * SS * SS;           // Scb tail (16M in)
  const size_t RS_OFF = SC_OFF + (size_t)BB * SS * SS * 2;       // after Scb
  u16* Wt  = (u16*)(ws + WT_OFF);
  u16* Q   = (u16*)(ws + Q_OFF);
  u16* Kb  = (u16*)(ws + K_OFF);
  u16* Vt  = (u16*)(ws + VT_OFF);
  u16* Scb = (u16*)(ws + SC_OFF);
  u16* xb  = (u16*)(ws + XB_OFF);
  float* rs = (float*)(ws + RS_OFF);

  hipLaunchKernelGGL(prep, dim3(2816), dim3(256), 0, stream, x, WQ, WK, WV, xb, Wt, rs);
  hipLaunchKernelGGL(qkv_a, dim3(64, 12), dim3(256), 0, stream, xb, Wt, Q, Kb, Vt);
  hipLaunchKernelGGL(qkv_b, dim3(64, 12), dim3(256), 0, stream, xb, Wt, Q, Kb, Vt);
  hipLaunchKernelGGL(scores_gemm, dim3(544), dim3(256), 0, stream, Q, Kb, Scb, rs);
  hipLaunchKernelGGL(pv_gemm, dim3(512), dim3(256), 0, stream, Scb, Vt, rs, out);
}

// Round 10
// 210.973 us; speedup vs baseline: 1.0311x; 1.0311x over previous
//
#include <hip/hip_runtime.h>
#include <stdint.h>

// SelfAttention: B=4, S=2048, D=1024, causal, single head of dim 1024.
// R15 = R13 exactly (revert R14's pv pairing map, which regressed 214->217.5).
// Best verified config: proven 128^2 core everywhere + XCD-chunked (%8)
// tile assignment for scores and pv + softmax-free algebra + compact ws.
// Accounting at 214us: ~46us harness fills (uncontrollable) + qkv 59us
// (structure ceiling) + scores ~32 + pv ~28 (both L2-optimized) + prep ~12.

typedef unsigned short u16;
typedef __attribute__((ext_vector_type(8))) short shortx8;  // 8 bf16 (4 VGPRs)
typedef __attribute__((ext_vector_type(4))) float floatx4;

static constexpr int BB = 4;
static constexpr int SS = 2048;
static constexpr int DD = 1024;

__device__ __forceinline__ u16 f2bf(float f) {
  union { float f; uint32_t u; } c; c.f = f;
  uint32_t u = c.u;
  return (u16)((u + 0x7fffu + ((u >> 16) & 1u)) >> 16);  // RNE
}

#define GLOAD_LDS16(g, l)                                                              \
  __builtin_amdgcn_global_load_lds((const __attribute__((address_space(1))) void*)(g), \
                                   (__attribute__((address_space(3))) void*)(l), 16, 0, 0)

// 128x128 C-tile GEMM core, BK=64, XOR-swizzled LDS (proven 888 TF structure).
__device__ __forceinline__ void gemm_core_128(
    const u16* __restrict__ A, const u16* __restrict__ Bt,
    int lda, int ldb, int m0, int n0, int kend, floatx4 acc[4][4])
{
  __shared__ u16 lA[128 * 64];  // [row][64], physical chunks swizzled
  __shared__ u16 lB[128 * 64];
  const int t = threadIdx.x;
  const int w = t >> 6, l = t & 63;
  const int wm = w >> 1, wn = w & 1;
  const int sr = l >> 3;                          // staging row within 8-row group
  const int scq = ((l & 7) ^ (l >> 3)) * 8;       // swizzled SOURCE chunk (elems)

#pragma unroll
  for (int i = 0; i < 4; ++i)
#pragma unroll
    for (int j = 0; j < 4; ++j)
      acc[i][j] = (floatx4){0.f, 0.f, 0.f, 0.f};

  const u16* Ab = A + (size_t)m0 * lda;
  const u16* Bb = Bt + (size_t)n0 * ldb;

  for (int k0 = 0; k0 < kend; k0 += 64) {
#pragma unroll
    for (int i = 0; i < 4; ++i) {
      const int row = w * 32 + i * 8;
      GLOAD_LDS16(Ab + (size_t)(row + sr) * lda + k0 + scq, &lA[row * 64]);
      GLOAD_LDS16(Bb + (size_t)(row + sr) * ldb + k0 + scq, &lB[row * 64]);
    }
    __syncthreads();  // drains vmcnt before barrier -> LDS visible

#pragma unroll
    for (int ks = 0; ks < 2; ++ks) {
      const int ca = ((ks * 4 + (l >> 4)) ^ (l & 7)) * 8;  // physical chunk (elems)
      shortx8 af[4], bf[4];
#pragma unroll
      for (int i = 0; i < 4; ++i)
        af[i] = *(const shortx8*)&lA[(wm * 64 + i * 16 + (l & 15)) * 64 + ca];
#pragma unroll
      for (int i = 0; i < 4; ++i)
        bf[i] = *(const shortx8*)&lB[(wn * 64 + i * 16 + (l & 15)) * 64 + ca];
#pragma unroll
      for (int i = 0; i < 4; ++i)
#pragma unroll
        for (int j = 0; j < 4; ++j)
          acc[i][j] = __builtin_amdgcn_mfma_f32_16x16x32_bf16(af[i], bf[j], acc[i][j], 0, 0, 0);
    }
    __syncthreads();  // protect LDS before next stage
  }
}

// ---- kernel 0: prep, grid-strided: blocks 0..2047 convert x (4x float4 per
//      thread) + zero rs; blocks 2048..2815 build Wt (64x64 transpose tiles) ----
__global__ __launch_bounds__(256) void prep(const float* __restrict__ x,
                                            const float* __restrict__ WQ,
                                            const float* __restrict__ WK,
                                            const float* __restrict__ WV,
                                            u16* __restrict__ xb,
                                            u16* __restrict__ Wt,
                                            float* __restrict__ rs) {
  __shared__ float tile[64][65];
  const int bid = blockIdx.x;
  const int t = threadIdx.x;
  if (bid < 2048) {  // xb = bf16(x), 4 float4 per thread
#pragma unroll
    for (int k = 0; k < 4; ++k) {
      const size_t i = (size_t)bid * 1024 + k * 256 + t;
      if (i < 8192) rs[i] = 0.f;  // zero row-sum accumulators (blocks 0..7)
      float4 v = ((const float4*)x)[i];
      ushort4 o;
      o.x = f2bf(v.x); o.y = f2bf(v.y); o.z = f2bf(v.z); o.w = f2bf(v.w);
      ((ushort4*)xb)[i] = o;
    }
    return;
  }
  // Wt[n][k] = bf16(W[k][n]), 64x64 tiles through LDS
  const int r = bid - 2048;      // 0..767
  const int wsel = r >> 8;       // 0..2
  const int rr = r & 255;
  const int k0 = (rr >> 4) * 64, n0 = (rr & 15) * 64;
  const float* W = wsel == 0 ? WQ : (wsel == 1 ? WK : WV);
  const int tx = t & 63, ty = t >> 6;
#pragma unroll
  for (int i = 0; i < 16; ++i)
    tile[ty + i * 4][tx] = W[(size_t)(k0 + ty + i * 4) * DD + n0 + tx];
  __syncthreads();
  u16* dst = Wt + (size_t)wsel * DD * DD;
#pragma unroll
  for (int i = 0; i < 16; ++i)
    dst[(size_t)(n0 + ty + i * 4) * DD + k0 + tx] = f2bf(tile[tx][ty + i * 4]);
}

// ---- kernels 1a/1b: fused QKV projection, M=8192 N=3072 K=1024, split into
//      two half-N launches (768 blocks each). Q,K row-major bf16; V written
//      TRANSPOSED into Vt[b][d][s]. ----
__device__ __forceinline__ void qkv_body(int m0, int n0t,
                                         const u16* __restrict__ x,
                                         const u16* __restrict__ Wt,
                                         u16* __restrict__ Q,
                                         u16* __restrict__ K,
                                         u16* __restrict__ Vt) {
  floatx4 acc[4][4];
  gemm_core_128(x, Wt, DD, DD, m0, n0t, DD, acc);

  const int t = threadIdx.x, w = t >> 6, l = t & 63;
  const int wm = w >> 1, wn = w & 1;

  if (n0t >= 2048) {  // V tile: write transposed. Each lane: 4 contiguous s per (i,j).
    const int bb = m0 >> 11;
    const int s0 = (m0 & 2047) + wm * 64 + (l >> 4) * 4;
    u16* vt = Vt + (size_t)bb * DD * SS;
#pragma unroll
    for (int i = 0; i < 4; ++i)
#pragma unroll
      for (int j = 0; j < 4; ++j) {
        const int n = (n0t - 2048) + wn * 64 + j * 16 + (l & 15);
        const int s = s0 + i * 16;
        ushort4 o4;
        o4.x = f2bf(acc[i][j][0]);
        o4.y = f2bf(acc[i][j][1]);
        o4.z = f2bf(acc[i][j][2]);
        o4.w = f2bf(acc[i][j][3]);
        *(ushort4*)(vt + (size_t)n * SS + s) = o4;
      }
    return;
  }

  u16* out = (n0t < 1024) ? Q : K;
  const int n0 = n0t & 1023;
#pragma unroll
  for (int i = 0; i < 4; ++i)
#pragma unroll
    for (int j = 0; j < 4; ++j)
#pragma unroll
      for (int r = 0; r < 4; ++r) {
        const int m = m0 + wm * 64 + i * 16 + (l >> 4) * 4 + r;
        const int n = n0 + wn * 64 + j * 16 + (l & 15);
        out[(size_t)m * DD + n] = f2bf(acc[i][j][r]);
      }
}

__global__ __launch_bounds__(256, 3) void qkv_a(const u16* __restrict__ x,
                                                const u16* __restrict__ Wt,
                                                u16* __restrict__ Q,
                                                u16* __restrict__ K,
                                                u16* __restrict__ Vt) {
  qkv_body(blockIdx.x * 128, blockIdx.y * 128, x, Wt, Q, K, Vt);
}

__global__ __launch_bounds__(256, 3) void qkv_b(const u16* __restrict__ x,
                                                const u16* __restrict__ Wt,
                                                u16* __restrict__ Q,
                                                u16* __restrict__ K,
                                                u16* __restrict__ Vt) {
  qkv_body(blockIdx.x * 128, (blockIdx.y + 12) * 128, x, Wt, Q, K, Vt);
}

// ---- kernel 2: E = bf16(exp(Q K^T / 32)) lower-tri blocks (diag masked),
//      + atomic per-row sums rs. XCD-chunked: sorted tile s = (bid&7)*68 +
//      bid>>3 gives each XCD 68 consecutive (b,mb,nb) tiles -> Q panels
//      shared within runs, K panels reused across mb within the 4MB L2. ----
__global__ __launch_bounds__(256, 3) void scores_gemm(const u16* __restrict__ Q,
                                                      const u16* __restrict__ Kt,
                                                      u16* __restrict__ Scb,
                                                      float* __restrict__ rs) {
  const int bid = blockIdx.x;                 // 0..543
  const int s = (bid & 7) * 68 + (bid >> 3);  // XCD-chunked sorted index
  const int b = s / 136;
  const int tcode = s - b * 136;              // 0..135
  int mb = (int)((sqrtf(8.0f * (float)tcode + 1.0f) - 1.0f) * 0.5f);
  while ((mb + 1) * (mb + 2) / 2 <= tcode) ++mb;  // fixup fp error
  while (mb * (mb + 1) / 2 > tcode) --mb;
  const int nb = tcode - mb * (mb + 1) / 2;
  const int m0 = mb * 128, n0 = nb * 128;

  floatx4 acc[4][4];
  gemm_core_128(Q + (size_t)b * SS * DD, Kt + (size_t)b * SS * DD, DD, DD, m0, n0, DD, acc);

  u16* out = Scb + (size_t)b * SS * SS;
  float* rsb = rs + (size_t)b * SS;
  const int t = threadIdx.x, w = t >> 6, l = t & 63;
  const int wm = w >> 1, wn = w & 1;
  const bool diag = (mb == nb);

  float rsum[4][4];  // [i][r] partial row sums
#pragma unroll
  for (int i = 0; i < 4; ++i)
#pragma unroll
    for (int r = 0; r < 4; ++r) rsum[i][r] = 0.f;

#pragma unroll
  for (int i = 0; i < 4; ++i)
#pragma unroll
    for (int j = 0; j < 4; ++j)
#pragma unroll
      for (int r = 0; r < 4; ++r) {
        const int lm = wm * 64 + i * 16 + (l >> 4) * 4 + r;  // local row
        const int ln = wn * 64 + j * 16 + (l & 15);          // local col
        float e = __expf(acc[i][j][r] * 0.03125f);           // 1/sqrt(1024)
        if (diag && ln > lm) e = 0.f;                        // causal mask
        out[(size_t)(m0 + lm) * SS + (n0 + ln)] = f2bf(e);
        rsum[i][r] += e;
      }

  // reduce over the 16 col-lanes (xor bits 0..3 mix only same-row lanes)
#pragma unroll
  for (int i = 0; i < 4; ++i)
#pragma unroll
    for (int r = 0; r < 4; ++r) {
      float s2 = rsum[i][r];
      s2 += __shfl_xor(s2, 1, 64);
      s2 += __shfl_xor(s2, 2, 64);
      s2 += __shfl_xor(s2, 4, 64);
      s2 += __shfl_xor(s2, 8, 64);
      if ((l & 15) == 0)
        atomicAdd(&rsb[m0 + wm * 64 + i * 16 + (l >> 4) * 4 + r], s2);
    }
}

// ---- kernel 3: O = (E V) / rs (causal K-range), fp32 out.
//      XCD-chunked: xcd = bid&7 owns (b = xcd>>1, nb half = xcd&1); r = bid>>3
//      iterates mb 15..0 (longest first) x 4 nb. Per-XCD work = 544 units
//      exactly; working set (1 P panel + 4 Vt panels ~2.5MB) fits L2. ----
__global__ __launch_bounds__(256, 3) void pv_gemm(const u16* __restrict__ P,
                                                  const u16* __restrict__ Vt,
                                                  const float* __restrict__ rs,
                                                  float* __restrict__ out) {
  const int bid = blockIdx.x;     // 0..511
  const int xcd = bid & 7, r = bid >> 3;       // r 0..63
  const int b = xcd >> 1;
  const int nb = (xcd & 1) * 4 + (r & 3);
  const int mb = 15 - (r >> 2);
  const int m0 = mb * 128, n0 = nb * 128;
  floatx4 acc[4][4];
  // rows m0..m0+127 only attend to keys k < m0+128
  gemm_core_128(P + (size_t)b * SS * SS, Vt + (size_t)b * DD * SS, SS, SS, m0, n0, m0 + 128, acc);

  float* o = out + (size_t)b * SS * DD;
  const float* rsb = rs + (size_t)b * SS;
  const int t = threadIdx.x, w = t >> 6, l = t & 63;
  const int wm = w >> 1, wn = w & 1;
#pragma unroll
  for (int i = 0; i < 4; ++i)
#pragma unroll
    for (int r2 = 0; r2 < 4; ++r2) {
      const int m = m0 + wm * 64 + i * 16 + (l >> 4) * 4 + r2;
      const float inv = 1.0f / rsb[m];   // row normalization (linear)
#pragma unroll
      for (int j2 = 0; j2 < 4; ++j2) {
        const int n = n0 + wn * 64 + j2 * 16 + (l & 15);
        o[(size_t)m * DD + n] = acc[i][j2][r2] * inv;
      }
    }
}

extern "C" void kernel_launch(void* const* d_in, const int* in_sizes, int n_in,
                              void* d_out, int out_size, void* d_ws, size_t ws_size,
                              hipStream_t stream) {
  const float* x  = (const float*)d_in[0];
  const float* WQ = (const float*)d_in[1];
  const float* WK = (const float*)d_in[2];
  const float* WV = (const float*)d_in[3];
  float* out = (float*)d_out;

  // workspace carve (bytes), ~88MB peak:
  //   Wt 6M | Q 16M | K 16M | Vt 16M | Scb(E) 32M | rs 32K, with xb (16M)
  //   aliased into Scb's tail half (xb dead before scores writes Scb).
  char* ws = (char*)d_ws;
  const size_t WT_OFF = 0;
  const size_t Q_OFF  = WT_OFF + (size_t)3072 * 1024 * 2;        // +6M
  const size_t K_OFF  = Q_OFF + (size_t)BB * SS * DD * 2;        // +16M
  const size_t VT_OFF = K_OFF + (size_t)BB * SS * DD * 2;        // +16M
  const size_t SC_OFF = VT_OFF + (size_t)BB * SS * DD * 2;       // +16M
  const size_t XB_OFF = SC_OFF + (size_t)BB * SS * SS;           // Scb tail (16M in)
  const size_t RS_OFF = SC_OFF + (size_t)BB * SS * SS * 2;       // after Scb
  u16* Wt  = (u16*)(ws + WT_OFF);
  u16* Q   = (u16*)(ws + Q_OFF);
  u16* Kb  = (u16*)(ws + K_OFF);
  u16* Vt  = (u16*)(ws + VT_OFF);
  u16* Scb = (u16*)(ws + SC_OFF);
  u16* xb  = (u16*)(ws + XB_OFF);
  float* rs = (float*)(ws + RS_OFF);

  hipLaunchKernelGGL(prep, dim3(2816), dim3(256), 0, stream, x, WQ, WK, WV, xb, Wt, rs);
  hipLaunchKernelGGL(qkv_a, dim3(64, 12), dim3(256), 0, stream, xb, Wt, Q, Kb, Vt);
  hipLaunchKernelGGL(qkv_b, dim3(64, 12), dim3(256), 0, stream, xb, Wt, Q, Kb, Vt);
  hipLaunchKernelGGL(scores_gemm, dim3(544), dim3(256), 0, stream, Q, Kb, Scb, rs);
  hipLaunchKernelGGL(pv_gemm, dim3(512), dim3(256), 0, stream, Scb, Vt, rs, out);
}